// Round 1
// baseline (3407.911 us; speedup 1.0000x reference)
//
#include <hip/hip_runtime.h>

// Sinkhorn distance, 8 batches x 2048 points x 2 dims, 50 iters, eps=0.1.
// v2: single persistent kernel for all 100 half-passes. Per-batch 64-block
// software barrier (release add / relaxed spin / acquire). j-side rank-2
// factors for BOTH directions live in VGPRs across all iterations; only the
// 8KB dual vector is reloaded per phase. Inner op: 2 FMA + exp2 + add.

#define P 2048
#define NB 8
constexpr float SCALE = 14.426950408889634f; // log2(e) / eps, eps = 0.1
constexpr float INV4S = 1.0f / (4.0f * SCALE);

typedef float vf4 __attribute__((ext_vector_type(4)));

// ws layout (floats):
// 0       jpackY float2[8*2048]   (32768 f)
// 32768   jpackX float2[8*2048]   (32768 f)
// 65536   rowX   float4[8*2048]   (65536 f)
// 131072  rowY   float4[8*2048]   (65536 f)
// 196608  u[16384]
// 212992  v[16384]
// 229376  partial[512]
// 229888  bar[8] (unsigned)

__global__ void setup_kernel(const float* __restrict__ x, const float* __restrict__ yy,
                             float2* __restrict__ jpY, float2* __restrict__ jpX,
                             float4* __restrict__ rowX, float4* __restrict__ rowY,
                             float* __restrict__ u, float* __restrict__ v,
                             float* __restrict__ partial, unsigned* __restrict__ bar) {
    const int n = blockIdx.x;
    const int t = threadIdx.x;
    __shared__ float redx[256], redy[256];
    float xm0[8], xm1[8], ym0[8], ym1[8];
    float sx = 0.f, sy = 0.f;
    #pragma unroll
    for (int k = 0; k < 8; ++k) {
        int p = t + 256 * k;
        size_t base = ((size_t)n * P + p) * 2;
        float a0 = x[base + 0];
        float a1 = x[base + 1];
        float b0 = yy[base + 0];
        float b1 = yy[base + 1];
        // mask = (x != -1); applied to BOTH x and y (per reference)
        float m0 = (a0 != -1.0f) ? 1.0f : 0.0f;
        float m1 = (a1 != -1.0f) ? 1.0f : 0.0f;
        a0 *= m0; a1 *= m1; b0 *= m0; b1 *= m1;
        xm0[k] = a0; xm1[k] = a1; ym0[k] = b0; ym1[k] = b1;
        sx = fmaf(a1, a1, sx);
        sy = fmaf(b1, b1, sy);
    }
    redx[t] = sx; redy[t] = sy;
    __syncthreads();
    for (int off = 128; off > 0; off >>= 1) {
        if (t < off) { redx[t] += redx[t + off]; redy[t] += redy[t + off]; }
        __syncthreads();
    }
    const float inv_sx = 1.0f / redx[0];
    const float inv_sy = 1.0f / redy[0];
    #pragma unroll
    for (int k = 0; k < 8; ++k) {
        int p = t + 256 * k;
        float a0 = xm0[k], a1 = xm1[k], b0 = ym0[k], b1 = ym1[k];
        float qx = fmaf(a0, a0, a1 * a1);
        float qy = fmaf(b0, b0, b1 * b1);
        float mu = a1 * a1 * inv_sx;
        float nu = b1 * b1 * inv_sy;
        // B = log2(marginal + 1e-8) + s*|pt|^2 (cancels dropped row constant)
        float Bmu = __builtin_amdgcn_logf(mu + 1e-8f) + SCALE * qx;
        float Bnu = __builtin_amdgcn_logf(nu + 1e-8f) + SCALE * qy;
        size_t idx = (size_t)n * P + p;
        rowX[idx] = make_float4(a0, a1, Bmu, 0.f);
        rowY[idx] = make_float4(b0, b1, Bnu, 0.f);
        jpX[idx] = make_float2(2.f * SCALE * a0, 2.f * SCALE * a1);
        jpY[idx] = make_float2(2.f * SCALE * b0, 2.f * SCALE * b1);
        u[idx] = 0.f;
        v[idx] = 0.f;
    }
    if (n == 0) {
        partial[t] = 0.f; partial[t + 256] = 0.f;
        if (t < 8) bar[t] = 0u;
    }
}

// Per-batch barrier across the 64 blocks owning one batch. Monotonic counter;
// release on arrival publishes this XCD's L2, acquire on departure invalidates.
__device__ __forceinline__ void batch_barrier(unsigned* bar, unsigned target) {
    __syncthreads();
    if (threadIdx.x == 0) {
        __hip_atomic_fetch_add(bar, 1u, __ATOMIC_RELEASE, __HIP_MEMORY_SCOPE_AGENT);
        int guard = 0;
        while (__hip_atomic_load(bar, __ATOMIC_RELAXED, __HIP_MEMORY_SCOPE_AGENT) < target) {
            __builtin_amdgcn_s_sleep(2);
            if (++guard > (1 << 22)) break;   // deadman: fail visibly, not hang
        }
        (void)__hip_atomic_load(bar, __ATOMIC_ACQUIRE, __HIP_MEMORY_SCOPE_AGENT);
    }
    __syncthreads();
}

// out_i = B_i - log2( sum_j 2^( V_j + Y0_j*x0_i + Y1_j*x1_i ) )
// j <-> (lane, k) mapping: j = lane*32 + k  (lane-contiguous, dwordx4 loads).
__device__ __forceinline__ float rowsum(const float (&Y0)[32], const float (&Y1)[32],
                                        const float (&V)[32], float x0, float x1) {
    float a0 = 0.f, a1 = 0.f, a2 = 0.f, a3 = 0.f;
    #pragma unroll
    for (int k = 0; k < 32; k += 4) {
        a0 += __builtin_amdgcn_exp2f(fmaf(Y1[k + 0], x1, fmaf(Y0[k + 0], x0, V[k + 0])));
        a1 += __builtin_amdgcn_exp2f(fmaf(Y1[k + 1], x1, fmaf(Y0[k + 1], x0, V[k + 1])));
        a2 += __builtin_amdgcn_exp2f(fmaf(Y1[k + 2], x1, fmaf(Y0[k + 2], x0, V[k + 2])));
        a3 += __builtin_amdgcn_exp2f(fmaf(Y1[k + 3], x1, fmaf(Y0[k + 3], x0, V[k + 3])));
    }
    return (a0 + a1) + (a2 + a3);
}

__device__ __forceinline__ void half_phase(const float (&Y0)[32], const float (&Y1)[32],
                                           const float* __restrict__ din,
                                           const float4* __restrict__ rdat,
                                           float* __restrict__ dout,
                                           const int lane, const int rowbase) {
    // V_j = dual_j - Q_j, Q recomputed from Y0,Y1: Q = (Y0^2 + Y1^2)/(4S)
    float V[32];
    const vf4* dp = (const vf4*)(din + (size_t)lane * 32);
    #pragma unroll
    for (int k8 = 0; k8 < 8; ++k8) {
        vf4 d = dp[k8];
        #pragma unroll
        for (int e = 0; e < 4; ++e) {
            int k = k8 * 4 + e;
            float q = fmaf(Y0[k], Y0[k], Y1[k] * Y1[k]);
            V[k] = fmaf(q, -INV4S, d[e]);
        }
    }
    float acc[8], Bs[8];
    #pragma unroll
    for (int r = 0; r < 8; ++r) {
        float4 rv = rdat[rowbase + r];     // wave-uniform
        Bs[r] = rv.z;
        acc[r] = rowsum(Y0, Y1, V, rv.x, rv.y);
    }
    // 8 independent butterflies (pipelined, not 8 serial dependent chains)
    #pragma unroll
    for (int r = 0; r < 8; ++r) {
        float a = acc[r];
        #pragma unroll
        for (int m = 1; m < 64; m <<= 1) a += __shfl_xor(a, m, 64);
        acc[r] = a;
    }
    if (lane == 0) {
        #pragma unroll
        for (int r = 0; r < 8; ++r)
            dout[rowbase + r] = Bs[r] - __builtin_amdgcn_logf(acc[r]);
    }
}

// 512 blocks x 256 threads, 2 blocks/CU -> all co-resident. batch = blk&7;
// each block owns 32 rows of its batch for BOTH half-updates.
__global__ __launch_bounds__(256, 2) void sinkhorn_iter_kernel(
        const float2* __restrict__ jpY, const float2* __restrict__ jpX,
        const float4* __restrict__ rowX, const float4* __restrict__ rowY,
        float* __restrict__ u, float* __restrict__ v, unsigned* __restrict__ bar) {
    const int blk = blockIdx.x;
    const int batch = blk & 7;
    const int blkin = blk >> 3;               // 0..63
    const int lane = threadIdx.x & 63;
    const int wave = threadIdx.x >> 6;        // 0..3
    const int rowbase = blkin * 32 + wave * 8;

    const float2* jY = jpY + (size_t)batch * P;
    const float2* jX = jpX + (size_t)batch * P;
    const float4* rX = rowX + (size_t)batch * P;
    const float4* rY = rowY + (size_t)batch * P;
    float* ub = u + (size_t)batch * P;
    float* vb = v + (size_t)batch * P;
    unsigned* mybar = bar + batch;

    // j-side factors for BOTH directions, resident in VGPRs for all 50 iters.
    float Yy0[32], Yy1[32], Yx0[32], Yx1[32];
    const vf4* py = (const vf4*)(jY + (size_t)lane * 32);
    const vf4* px = (const vf4*)(jX + (size_t)lane * 32);
    #pragma unroll
    for (int m = 0; m < 16; ++m) {
        vf4 qy = py[m];
        vf4 qx = px[m];
        Yy0[2 * m] = qy[0]; Yy1[2 * m] = qy[1];
        Yy0[2 * m + 1] = qy[2]; Yy1[2 * m + 1] = qy[3];
        Yx0[2 * m] = qx[0]; Yx1[2 * m] = qx[1];
        Yx0[2 * m + 1] = qx[2]; Yx1[2 * m + 1] = qx[3];
    }

    unsigned tgt = 0;
    for (int it = 0; it < 50; ++it) {
        // u-update: reduce over j (y side), reads v, writes u
        half_phase(Yy0, Yy1, vb, rX, ub, lane, rowbase);
        tgt += 64; batch_barrier(mybar, tgt);
        // v-update: reduce over i (x side), reads u, writes v
        half_phase(Yx0, Yx1, ub, rY, vb, lane, rowbase);
        if (it < 49) { tgt += 64; batch_barrier(mybar, tgt); }
    }
}

// Final: pi = 2^(u~_i + v~_j - s*C_ij), C, and cost partials.
__global__ void final_kernel(const float4* __restrict__ rowX, const float4* __restrict__ rowY,
                             const float* __restrict__ u, const float* __restrict__ v,
                             float* __restrict__ out, float* __restrict__ partial) {
    const int blk = blockIdx.x;
    const int batch = blk & 7;
    const int i = blk >> 3;
    const int t = threadIdx.x;

    const float4 rx = rowX[(size_t)batch * P + i];
    const float ui = u[(size_t)batch * P + i];
    const float x0 = rx.x, x1 = rx.y;

    float* pi_out = out + 8 + (size_t)batch * P * P + (size_t)i * P;
    float* C_out = pi_out + (size_t)NB * P * P;
    const float4* ry = rowY + (size_t)batch * P;
    const float* vv = v + (size_t)batch * P;

    float costacc = 0.f;
    #pragma unroll
    for (int c = 0; c < 2; ++c) {
        const int j0 = c * 1024 + t * 4;
        vf4 vj = *(const vf4*)(vv + j0);
        vf4 Cv, Pv;
        #pragma unroll
        for (int e = 0; e < 4; ++e) {
            float4 q = ry[j0 + e];
            float dx = x0 - q.x;
            float dy = x1 - q.y;
            float Cj = fmaf(dy, dy, dx * dx);
            float pj = __builtin_amdgcn_exp2f(fmaf(Cj, -SCALE, ui + vj[e]));
            Cv[e] = Cj;
            Pv[e] = pj;
            costacc = fmaf(pj, Cj, costacc);
        }
        __builtin_nontemporal_store(Pv, (vf4*)(pi_out + j0));
        __builtin_nontemporal_store(Cv, (vf4*)(C_out + j0));
    }

    #pragma unroll
    for (int m = 1; m < 64; m <<= 1) costacc += __shfl_xor(costacc, m, 64);
    __shared__ float sred[4];
    const int wave = t >> 6, lane = t & 63;
    if (lane == 0) sred[wave] = costacc;
    __syncthreads();
    if (t == 0) {
        float s = sred[0] + sred[1] + sred[2] + sred[3];
        atomicAdd(&partial[batch * 64 + (i & 63)], s);
    }
}

__global__ void costreduce_kernel(const float* __restrict__ partial, float* __restrict__ out) {
    const int t = threadIdx.x; // 512 threads: wave w reduces batch w's 64 slots
    float val = partial[t];
    #pragma unroll
    for (int m = 1; m < 64; m <<= 1) val += __shfl_xor(val, m, 64);
    if ((t & 63) == 0) out[t >> 6] = val;
}

extern "C" void kernel_launch(void* const* d_in, const int* in_sizes, int n_in,
                              void* d_out, int out_size, void* d_ws, size_t ws_size,
                              hipStream_t stream) {
    const float* x = (const float*)d_in[0];
    const float* y = (const float*)d_in[1];
    float* out = (float*)d_out;
    float* ws = (float*)d_ws;

    float2* jpY = (float2*)ws;
    float2* jpX = (float2*)(ws + 32768);
    float4* rowX = (float4*)(ws + 65536);
    float4* rowY = (float4*)(ws + 131072);
    float* u = ws + 196608;
    float* v = ws + 196608 + 16384;
    float* partial = ws + 196608 + 32768;
    unsigned* bar = (unsigned*)(ws + 196608 + 32768 + 512);

    setup_kernel<<<8, 256, 0, stream>>>(x, y, jpY, jpX, rowX, rowY, u, v, partial, bar);
    sinkhorn_iter_kernel<<<512, 256, 0, stream>>>(jpY, jpX, rowX, rowY, u, v, bar);
    final_kernel<<<16384, 256, 0, stream>>>(rowX, rowY, u, v, out, partial);
    costreduce_kernel<<<1, 512, 0, stream>>>(partial, out);
}

// Round 2
// 2238.611 us; speedup vs baseline: 1.5223x; 1.5223x over previous
//
#include <hip/hip_runtime.h>

// Sinkhorn distance, 8 batches x 2048 points x 2 dims, 50 iters, eps=0.1.
// v3: persistent kernel (all 100 half-passes), barrier redesigned:
//  - per-batch arrive counter padded to its own 256B line (RMW traffic only,
//    64 adds per phase)
//  - per-batch epoch flag on a separate 256B line; last arriver publishes,
//    63 followers poll with pure loads at s_sleep(16) cadence (~0.43us)
// j-side rank-2 factors for BOTH directions live in VGPRs across all 50
// iterations; only the 8KB dual vector is reloaded per phase.

#define P 2048
#define NB 8
constexpr float SCALE = 14.426950408889634f; // log2(e) / eps, eps = 0.1
constexpr float INV4S = 1.0f / (4.0f * SCALE);

typedef float vf4 __attribute__((ext_vector_type(4)));

// ws layout (floats):
// 0       jpY   float2[8*2048]   (32768 f)
// 32768   jpX   float2[8*2048]   (32768 f)
// 65536   rowX  float4[8*2048]   (65536 f)
// 131072  rowY  float4[8*2048]   (65536 f)
// 196608  u[16384]
// 212992  v[16384]
// 229376  partial[512]
// 229888  barrier area: unsigned[1024]
//         arrive[b] at u32 index b*64  (256B stride)
//         epoch[b]  at u32 index 512 + b*64

__global__ void setup_kernel(const float* __restrict__ x, const float* __restrict__ yy,
                             float2* __restrict__ jpY, float2* __restrict__ jpX,
                             float4* __restrict__ rowX, float4* __restrict__ rowY,
                             float* __restrict__ u, float* __restrict__ v,
                             float* __restrict__ partial, unsigned* __restrict__ bar) {
    const int n = blockIdx.x;
    const int t = threadIdx.x;
    __shared__ float redx[256], redy[256];
    float xm0[8], xm1[8], ym0[8], ym1[8];
    float sx = 0.f, sy = 0.f;
    #pragma unroll
    for (int k = 0; k < 8; ++k) {
        int p = t + 256 * k;
        size_t base = ((size_t)n * P + p) * 2;
        float a0 = x[base + 0];
        float a1 = x[base + 1];
        float b0 = yy[base + 0];
        float b1 = yy[base + 1];
        // mask = (x != -1); applied to BOTH x and y (per reference)
        float m0 = (a0 != -1.0f) ? 1.0f : 0.0f;
        float m1 = (a1 != -1.0f) ? 1.0f : 0.0f;
        a0 *= m0; a1 *= m1; b0 *= m0; b1 *= m1;
        xm0[k] = a0; xm1[k] = a1; ym0[k] = b0; ym1[k] = b1;
        sx = fmaf(a1, a1, sx);
        sy = fmaf(b1, b1, sy);
    }
    redx[t] = sx; redy[t] = sy;
    __syncthreads();
    for (int off = 128; off > 0; off >>= 1) {
        if (t < off) { redx[t] += redx[t + off]; redy[t] += redy[t + off]; }
        __syncthreads();
    }
    const float inv_sx = 1.0f / redx[0];
    const float inv_sy = 1.0f / redy[0];
    #pragma unroll
    for (int k = 0; k < 8; ++k) {
        int p = t + 256 * k;
        float a0 = xm0[k], a1 = xm1[k], b0 = ym0[k], b1 = ym1[k];
        float qx = fmaf(a0, a0, a1 * a1);
        float qy = fmaf(b0, b0, b1 * b1);
        float mu = a1 * a1 * inv_sx;
        float nu = b1 * b1 * inv_sy;
        // B = log2(marginal + 1e-8) + s*|pt|^2 (cancels dropped row constant)
        float Bmu = __builtin_amdgcn_logf(mu + 1e-8f) + SCALE * qx;
        float Bnu = __builtin_amdgcn_logf(nu + 1e-8f) + SCALE * qy;
        size_t idx = (size_t)n * P + p;
        rowX[idx] = make_float4(a0, a1, Bmu, 0.f);
        rowY[idx] = make_float4(b0, b1, Bnu, 0.f);
        jpX[idx] = make_float2(2.f * SCALE * a0, 2.f * SCALE * a1);
        jpY[idx] = make_float2(2.f * SCALE * b0, 2.f * SCALE * b1);
        u[idx] = 0.f;
        v[idx] = 0.f;
    }
    if (n == 0) {
        partial[t] = 0.f; partial[t + 256] = 0.f;
        // zero the entire 1024-u32 barrier area (re-zeroed every launch /
        // graph replay, stream-ordered before the iter kernel)
        bar[t] = 0u; bar[t + 256] = 0u; bar[t + 512] = 0u; bar[t + 768] = 0u;
    }
}

// Per-batch barrier across the 64 blocks owning one batch.
// arrive: monotonic counter, one ACQ_REL add per block per phase (the only
// RMW traffic on that line). Last arriver release-publishes the epoch flag;
// followers poll it with relaxed loads at ~0.43us cadence, then acquire.
__device__ __forceinline__ void batch_barrier(unsigned* __restrict__ arrive,
                                              unsigned* __restrict__ epoch,
                                              unsigned target, unsigned ep) {
    __syncthreads();
    if (threadIdx.x == 0) {
        unsigned old = __hip_atomic_fetch_add(arrive, 1u, __ATOMIC_ACQ_REL,
                                              __HIP_MEMORY_SCOPE_AGENT);
        if (old == target - 1u) {
            __hip_atomic_store(epoch, ep, __ATOMIC_RELEASE, __HIP_MEMORY_SCOPE_AGENT);
        } else {
            int guard = 0;
            while (__hip_atomic_load(epoch, __ATOMIC_RELAXED,
                                     __HIP_MEMORY_SCOPE_AGENT) < ep) {
                __builtin_amdgcn_s_sleep(16);   // ~1024 cycles between polls
                if (++guard > (1 << 18)) break; // deadman: fail visibly, not hang
            }
            (void)__hip_atomic_load(epoch, __ATOMIC_ACQUIRE, __HIP_MEMORY_SCOPE_AGENT);
        }
    }
    __syncthreads();
}

// out_i = B_i - log2( sum_j 2^( V_j + Y0_j*x0_i + Y1_j*x1_i ) )
// j <-> (lane, k) mapping: j = lane*32 + k  (lane-contiguous, dwordx4 loads).
__device__ __forceinline__ float rowsum(const float (&Y0)[32], const float (&Y1)[32],
                                        const float (&V)[32], float x0, float x1) {
    float a0 = 0.f, a1 = 0.f, a2 = 0.f, a3 = 0.f;
    #pragma unroll
    for (int k = 0; k < 32; k += 4) {
        a0 += __builtin_amdgcn_exp2f(fmaf(Y1[k + 0], x1, fmaf(Y0[k + 0], x0, V[k + 0])));
        a1 += __builtin_amdgcn_exp2f(fmaf(Y1[k + 1], x1, fmaf(Y0[k + 1], x0, V[k + 1])));
        a2 += __builtin_amdgcn_exp2f(fmaf(Y1[k + 2], x1, fmaf(Y0[k + 2], x0, V[k + 2])));
        a3 += __builtin_amdgcn_exp2f(fmaf(Y1[k + 3], x1, fmaf(Y0[k + 3], x0, V[k + 3])));
    }
    return (a0 + a1) + (a2 + a3);
}

__device__ __forceinline__ void half_phase(const float (&Y0)[32], const float (&Y1)[32],
                                           const float* __restrict__ din,
                                           const float4* __restrict__ rdat,
                                           float* __restrict__ dout,
                                           const int lane, const int rowbase) {
    // V_j = dual_j - Q_j, Q recomputed from Y0,Y1: Q = (Y0^2 + Y1^2)/(4S)
    float V[32];
    const vf4* dp = (const vf4*)(din + (size_t)lane * 32);
    #pragma unroll
    for (int k8 = 0; k8 < 8; ++k8) {
        vf4 d = dp[k8];
        #pragma unroll
        for (int e = 0; e < 4; ++e) {
            int k = k8 * 4 + e;
            float q = fmaf(Y0[k], Y0[k], Y1[k] * Y1[k]);
            V[k] = fmaf(q, -INV4S, d[e]);
        }
    }
    float acc[8], Bs[8];
    #pragma unroll
    for (int r = 0; r < 8; ++r) {
        float4 rv = rdat[rowbase + r];     // wave-uniform
        Bs[r] = rv.z;
        acc[r] = rowsum(Y0, Y1, V, rv.x, rv.y);
    }
    // 8 independent butterflies (pipelined, not 8 serial dependent chains)
    #pragma unroll
    for (int r = 0; r < 8; ++r) {
        float a = acc[r];
        #pragma unroll
        for (int m = 1; m < 64; m <<= 1) a += __shfl_xor(a, m, 64);
        acc[r] = a;
    }
    if (lane == 0) {
        #pragma unroll
        for (int r = 0; r < 8; ++r)
            dout[rowbase + r] = Bs[r] - __builtin_amdgcn_logf(acc[r]);
    }
}

// 512 blocks x 256 threads, 2 blocks/CU -> all co-resident. batch = blk&7
// (round-robin dispatch puts each batch's 64 blocks on one XCD -> dual
// vectors stay XCD-local). Each block owns 32 rows for BOTH half-updates.
__global__ __launch_bounds__(256, 2) void sinkhorn_iter_kernel(
        const float2* __restrict__ jpY, const float2* __restrict__ jpX,
        const float4* __restrict__ rowX, const float4* __restrict__ rowY,
        float* __restrict__ u, float* __restrict__ v, unsigned* __restrict__ bar) {
    const int blk = blockIdx.x;
    const int batch = blk & 7;
    const int blkin = blk >> 3;               // 0..63
    const int lane = threadIdx.x & 63;
    const int wave = threadIdx.x >> 6;        // 0..3
    const int rowbase = blkin * 32 + wave * 8;

    const float2* jY = jpY + (size_t)batch * P;
    const float2* jX = jpX + (size_t)batch * P;
    const float4* rX = rowX + (size_t)batch * P;
    const float4* rY = rowY + (size_t)batch * P;
    float* ub = u + (size_t)batch * P;
    float* vb = v + (size_t)batch * P;
    unsigned* arrive = bar + (size_t)batch * 64;        // 256B line per batch
    unsigned* epoch = bar + 512 + (size_t)batch * 64;   // separate 256B line

    // j-side factors for BOTH directions, resident in VGPRs for all 50 iters.
    float Yy0[32], Yy1[32], Yx0[32], Yx1[32];
    const vf4* py = (const vf4*)(jY + (size_t)lane * 32);
    const vf4* px = (const vf4*)(jX + (size_t)lane * 32);
    #pragma unroll
    for (int m = 0; m < 16; ++m) {
        vf4 qy = py[m];
        vf4 qx = px[m];
        Yy0[2 * m] = qy[0]; Yy1[2 * m] = qy[1];
        Yy0[2 * m + 1] = qy[2]; Yy1[2 * m + 1] = qy[3];
        Yx0[2 * m] = qx[0]; Yx1[2 * m] = qx[1];
        Yx0[2 * m + 1] = qx[2]; Yx1[2 * m + 1] = qx[3];
    }

    unsigned cnt = 0, ep = 0;
    for (int it = 0; it < 50; ++it) {
        // u-update: reduce over j (y side), reads v, writes u
        half_phase(Yy0, Yy1, vb, rX, ub, lane, rowbase);
        cnt += 64; ++ep;
        batch_barrier(arrive, epoch, cnt, ep);
        // v-update: reduce over i (x side), reads u, writes v
        half_phase(Yx0, Yx1, ub, rY, vb, lane, rowbase);
        if (it < 49) {
            cnt += 64; ++ep;
            batch_barrier(arrive, epoch, cnt, ep);
        }
    }
}

// Final: pi = 2^(u~_i + v~_j - s*C_ij), C, and cost partials.
__global__ void final_kernel(const float4* __restrict__ rowX, const float4* __restrict__ rowY,
                             const float* __restrict__ u, const float* __restrict__ v,
                             float* __restrict__ out, float* __restrict__ partial) {
    const int blk = blockIdx.x;
    const int batch = blk & 7;
    const int i = blk >> 3;
    const int t = threadIdx.x;

    const float4 rx = rowX[(size_t)batch * P + i];
    const float ui = u[(size_t)batch * P + i];
    const float x0 = rx.x, x1 = rx.y;

    float* pi_out = out + 8 + (size_t)batch * P * P + (size_t)i * P;
    float* C_out = pi_out + (size_t)NB * P * P;
    const float4* ry = rowY + (size_t)batch * P;
    const float* vv = v + (size_t)batch * P;

    float costacc = 0.f;
    #pragma unroll
    for (int c = 0; c < 2; ++c) {
        const int j0 = c * 1024 + t * 4;
        vf4 vj = *(const vf4*)(vv + j0);
        vf4 Cv, Pv;
        #pragma unroll
        for (int e = 0; e < 4; ++e) {
            float4 q = ry[j0 + e];
            float dx = x0 - q.x;
            float dy = x1 - q.y;
            float Cj = fmaf(dy, dy, dx * dx);
            float pj = __builtin_amdgcn_exp2f(fmaf(Cj, -SCALE, ui + vj[e]));
            Cv[e] = Cj;
            Pv[e] = pj;
            costacc = fmaf(pj, Cj, costacc);
        }
        __builtin_nontemporal_store(Pv, (vf4*)(pi_out + j0));
        __builtin_nontemporal_store(Cv, (vf4*)(C_out + j0));
    }

    #pragma unroll
    for (int m = 1; m < 64; m <<= 1) costacc += __shfl_xor(costacc, m, 64);
    __shared__ float sred[4];
    const int wave = t >> 6, lane = t & 63;
    if (lane == 0) sred[wave] = costacc;
    __syncthreads();
    if (t == 0) {
        float s = sred[0] + sred[1] + sred[2] + sred[3];
        atomicAdd(&partial[batch * 64 + (i & 63)], s);
    }
}

__global__ void costreduce_kernel(const float* __restrict__ partial, float* __restrict__ out) {
    const int t = threadIdx.x; // 512 threads: wave w reduces batch w's 64 slots
    float val = partial[t];
    #pragma unroll
    for (int m = 1; m < 64; m <<= 1) val += __shfl_xor(val, m, 64);
    if ((t & 63) == 0) out[t >> 6] = val;
}

extern "C" void kernel_launch(void* const* d_in, const int* in_sizes, int n_in,
                              void* d_out, int out_size, void* d_ws, size_t ws_size,
                              hipStream_t stream) {
    const float* x = (const float*)d_in[0];
    const float* y = (const float*)d_in[1];
    float* out = (float*)d_out;
    float* ws = (float*)d_ws;

    float2* jpY = (float2*)ws;
    float2* jpX = (float2*)(ws + 32768);
    float4* rowX = (float4*)(ws + 65536);
    float4* rowY = (float4*)(ws + 131072);
    float* u = ws + 196608;
    float* v = ws + 196608 + 16384;
    float* partial = ws + 196608 + 32768;
    unsigned* bar = (unsigned*)(ws + 196608 + 32768 + 512);

    setup_kernel<<<8, 256, 0, stream>>>(x, y, jpY, jpX, rowX, rowY, u, v, partial, bar);
    sinkhorn_iter_kernel<<<512, 256, 0, stream>>>(jpY, jpX, rowX, rowY, u, v, bar);
    final_kernel<<<16384, 256, 0, stream>>>(rowX, rowY, u, v, out, partial);
    costreduce_kernel<<<1, 512, 0, stream>>>(partial, out);
}